// Round 1
// baseline (304.384 us; speedup 1.0000x reference)
//
#include <hip/hip_runtime.h>
#include <math.h>

#define THREADS 256
#define TILE 2048

__device__ __forceinline__ float warp_block_reduce(float v, float* red) {
    // 64-lane wave reduce
    #pragma unroll
    for (int off = 32; off > 0; off >>= 1) v += __shfl_down(v, off, 64);
    int wid  = threadIdx.x >> 6;
    int lane = threadIdx.x & 63;
    if (lane == 0) red[wid] = v;
    __syncthreads();
    float s = 0.f;
    if (threadIdx.x == 0) {
        #pragma unroll
        for (int w = 0; w < THREADS / 64; ++w) s += red[w];
    }
    return s;
}

// role 0: queries = gt,   targets = pred, weight 0.8  -> acc[0]
// role 1: queries = pred, targets = gt,   weight 0.2  -> acc[0]
// role 2: queries = pred, targets = pred, 4-NN uniform loss -> acc[1]
__global__ __launch_bounds__(THREADS) void upsample_scan_kernel(
    const float* __restrict__ pred, const float* __restrict__ gt,
    const float* __restrict__ radius, float* __restrict__ acc,
    int B, int N, int chunksPerBatch)
{
    __shared__ float4 tgt[TILE];
    __shared__ float red[THREADS / 64];

    const float FLT_INF = 3.4e38f;
    const float RADIUS = 0.07f;
    const float INV_H2 = 1.0f / (0.03f * 0.03f);
    const float EPSV = 1e-12f;

    int blocksPerRole = B * chunksPerBatch;
    int role  = blockIdx.x / blocksPerRole;
    int rem   = blockIdx.x % blocksPerRole;
    int b     = rem / chunksPerBatch;
    int chunk = rem % chunksPerBatch;
    int i     = chunk * THREADS + (int)threadIdx.x;   // query idx within batch

    const float* Q  = (role == 0) ? gt : pred;
    const float* T  = (role == 1) ? gt : pred;
    const float* qb = Q + (size_t)b * N * 3;
    const float* tb = T + (size_t)b * N * 3;

    bool valid = (i < N);
    float qx = 0.f, qy = 0.f, qz = 0.f;
    if (valid) { qx = qb[i * 3 + 0]; qy = qb[i * 3 + 1]; qz = qb[i * 3 + 2]; }
    float na = qx * qx + qy * qy + qz * qz;

    float best = FLT_INF;                              // chamfer roles
    float b0 = FLT_INF, b1 = FLT_INF, b2 = FLT_INF, b3 = FLT_INF; // knn role

    for (int t0 = 0; t0 < N; t0 += TILE) {
        int cnt = min(TILE, N - t0);
        for (int k = threadIdx.x; k < cnt; k += THREADS) {
            float x = tb[(size_t)(t0 + k) * 3 + 0];
            float y = tb[(size_t)(t0 + k) * 3 + 1];
            float z = tb[(size_t)(t0 + k) * 3 + 2];
            tgt[k] = make_float4(x, y, z, fmaf(x, x, fmaf(y, y, z * z)));
        }
        __syncthreads();

        if (role < 2) {
            for (int j = 0; j < cnt; ++j) {
                float4 t = tgt[j];
                float dot = fmaf(qx, t.x, fmaf(qy, t.y, qz * t.z));
                float c = fmaf(-2.f, dot, t.w);      // nb - 2*dot  (na added later)
                best = fminf(best, c);
            }
        } else {
            for (int j = 0; j < cnt; ++j) {
                float4 t = tgt[j];
                float dot = fmaf(qx, t.x, fmaf(qy, t.y, qz * t.z));
                float c = fmaf(-2.f, dot, t.w);
                if (t0 + j == i) c = FLT_INF;        // exclude self
                if (c < b3) {                        // rare sorted-insert
                    float m = c, n;
                    n = fminf(b0, m); m = fmaxf(b0, m); b0 = n;
                    n = fminf(b1, m); m = fmaxf(b1, m); b1 = n;
                    n = fminf(b2, m); m = fmaxf(b2, m); b2 = n;
                    b3 = m;
                }
            }
        }
        __syncthreads();
    }

    float contrib = 0.f;
    if (valid) {
        float inv_r = 1.0f / radius[b];
        if (role < 2) {
            float w = (role == 0) ? 0.8f : 0.2f;
            contrib = w * inv_r * (na + best);
        } else {
            float bs0 = b0, bs1 = b1, bs2 = b2, bs3 = b3;
            float s = 0.f;
            float bss[4] = {bs0, bs1, bs2, bs3};
            #pragma unroll
            for (int k = 0; k < 4; ++k) {
                float d2 = fmaxf(na + bss[k], EPSV);
                float dist = sqrtf(d2);
                float wgt = __expf(-d2 * INV_H2);
                s += (RADIUS - dist) * wgt;
            }
            contrib = s;
        }
    }

    float blocksum = warp_block_reduce(contrib, red);
    if (threadIdx.x == 0) {
        atomicAdd(&acc[role < 2 ? 0 : 1], blocksum);
    }
}

__global__ void upsample_final_kernel(const float* __restrict__ acc,
                                      float* __restrict__ out,
                                      float invCd, float invUni)
{
    out[0] = fmaf(acc[0], invCd, 0.1f * acc[1] * invUni);
}

extern "C" void kernel_launch(void* const* d_in, const int* in_sizes, int n_in,
                              void* d_out, int out_size, void* d_ws, size_t ws_size,
                              hipStream_t stream) {
    const float* pred   = (const float*)d_in[0];
    const float* gt     = (const float*)d_in[1];
    const float* radius = (const float*)d_in[2];
    float* out = (float*)d_out;
    float* acc = (float*)d_ws;

    int B = in_sizes[2];                 // pcd_radius has B elements
    int N = in_sizes[0] / (3 * B);       // pred is B*N*3

    hipMemsetAsync(acc, 0, 2 * sizeof(float), stream);

    int chunksPerBatch = (N + THREADS - 1) / THREADS;
    int blocks = 3 * B * chunksPerBatch;
    upsample_scan_kernel<<<blocks, THREADS, 0, stream>>>(pred, gt, radius, acc,
                                                         B, N, chunksPerBatch);

    float invCd  = 1.0f / ((float)B * (float)N);
    float invUni = 1.0f / ((float)B * (float)N * 4.0f);
    upsample_final_kernel<<<1, 1, 0, stream>>>(acc, out, invCd, invUni);
}

// Round 2
// 116.860 us; speedup vs baseline: 2.6047x; 2.6047x over previous
//
#include <hip/hip_runtime.h>
#include <math.h>

#define THREADS 256
#define QB 64            // queries per block (one per lane)
#define TILE 1024        // targets staged in LDS per tile
#define NWAVE 4

__global__ __launch_bounds__(THREADS) void upsample_scan_kernel(
    const float* __restrict__ pred, const float* __restrict__ gt,
    const float* __restrict__ radius, float* __restrict__ acc,
    int B, int N, int chunksPerBatch)
{
    __shared__ float4 tgt[TILE];
    __shared__ float part[NWAVE][QB][4];   // partial min (slot 0) or partial top-4

    const float FLT_INF = 3.4e38f;
    const float RADIUS = 0.07f;
    const float INV_H2 = 1.0f / (0.03f * 0.03f);
    const float EPSV = 1e-12f;

    int blocksPerRole = B * chunksPerBatch;
    int role  = blockIdx.x / blocksPerRole;      // 0: gt->pred, 1: pred->gt, 2: pred knn
    int rem   = blockIdx.x % blocksPerRole;
    int b     = rem / chunksPerBatch;
    int chunk = rem % chunksPerBatch;

    int w = threadIdx.x >> 6;                    // wave id: target slice
    int l = threadIdx.x & 63;                    // lane id: query
    int i = chunk * QB + l;                      // query idx within batch

    const float* Q  = (role == 0) ? gt : pred;
    const float* T  = (role == 1) ? gt : pred;
    const float* qb = Q + (size_t)b * N * 3;
    const float* tb = T + (size_t)b * N * 3;

    bool valid = (i < N);
    float qx = 0.f, qy = 0.f, qz = 0.f;
    if (valid) { qx = qb[i * 3 + 0]; qy = qb[i * 3 + 1]; qz = qb[i * 3 + 2]; }
    float na = fmaf(qx, qx, fmaf(qy, qy, qz * qz));

    float m0 = FLT_INF, m1 = FLT_INF, m2 = FLT_INF, m3 = FLT_INF;  // chamfer
    float b0 = FLT_INF, b1 = FLT_INF, b2 = FLT_INF, b3 = FLT_INF;  // knn top-4

    for (int t0 = 0; t0 < N; t0 += TILE) {
        int cnt = min(TILE, N - t0);
        for (int k = threadIdx.x; k < cnt; k += THREADS) {
            float x = tb[(size_t)(t0 + k) * 3 + 0];
            float y = tb[(size_t)(t0 + k) * 3 + 1];
            float z = tb[(size_t)(t0 + k) * 3 + 2];
            tgt[k] = make_float4(x, y, z, fmaf(x, x, fmaf(y, y, z * z)));
        }
        __syncthreads();

        int seg  = (cnt + NWAVE - 1) / NWAVE;
        int jbeg = w * seg;
        int jend = min(jbeg + seg, cnt);

        if (role < 2) {
            int j = jbeg;
            for (; j + 3 < jend; j += 4) {
                float4 t0v = tgt[j], t1v = tgt[j + 1], t2v = tgt[j + 2], t3v = tgt[j + 3];
                float c0 = fmaf(-2.f, fmaf(qx, t0v.x, fmaf(qy, t0v.y, qz * t0v.z)), t0v.w);
                float c1 = fmaf(-2.f, fmaf(qx, t1v.x, fmaf(qy, t1v.y, qz * t1v.z)), t1v.w);
                float c2 = fmaf(-2.f, fmaf(qx, t2v.x, fmaf(qy, t2v.y, qz * t2v.z)), t2v.w);
                float c3 = fmaf(-2.f, fmaf(qx, t3v.x, fmaf(qy, t3v.y, qz * t3v.z)), t3v.w);
                m0 = fminf(m0, c0); m1 = fminf(m1, c1);
                m2 = fminf(m2, c2); m3 = fminf(m3, c3);
            }
            for (; j < jend; ++j) {
                float4 t = tgt[j];
                float c = fmaf(-2.f, fmaf(qx, t.x, fmaf(qy, t.y, qz * t.z)), t.w);
                m0 = fminf(m0, c);
            }
        } else {
            int j = jbeg;
            for (; j + 3 < jend; j += 4) {
                float4 t0v = tgt[j], t1v = tgt[j + 1], t2v = tgt[j + 2], t3v = tgt[j + 3];
                float c0 = fmaf(-2.f, fmaf(qx, t0v.x, fmaf(qy, t0v.y, qz * t0v.z)), t0v.w);
                float c1 = fmaf(-2.f, fmaf(qx, t1v.x, fmaf(qy, t1v.y, qz * t1v.z)), t1v.w);
                float c2 = fmaf(-2.f, fmaf(qx, t2v.x, fmaf(qy, t2v.y, qz * t2v.z)), t2v.w);
                float c3 = fmaf(-2.f, fmaf(qx, t3v.x, fmaf(qy, t3v.y, qz * t3v.z)), t3v.w);
                if (t0 + j + 0 == i) c0 = FLT_INF;
                if (t0 + j + 1 == i) c1 = FLT_INF;
                if (t0 + j + 2 == i) c2 = FLT_INF;
                if (t0 + j + 3 == i) c3 = FLT_INF;
                #pragma unroll
                for (int u = 0; u < 4; ++u) {
                    float c = (u == 0) ? c0 : (u == 1) ? c1 : (u == 2) ? c2 : c3;
                    if (c < b3) {
                        float m = c, n;
                        n = fminf(b0, m); m = fmaxf(b0, m); b0 = n;
                        n = fminf(b1, m); m = fmaxf(b1, m); b1 = n;
                        n = fminf(b2, m); m = fmaxf(b2, m); b2 = n;
                        b3 = m;
                    }
                }
            }
            for (; j < jend; ++j) {
                float4 t = tgt[j];
                float c = fmaf(-2.f, fmaf(qx, t.x, fmaf(qy, t.y, qz * t.z)), t.w);
                if (t0 + j == i) c = FLT_INF;
                if (c < b3) {
                    float m = c, n;
                    n = fminf(b0, m); m = fmaxf(b0, m); b0 = n;
                    n = fminf(b1, m); m = fmaxf(b1, m); b1 = n;
                    n = fminf(b2, m); m = fmaxf(b2, m); b2 = n;
                    b3 = m;
                }
            }
        }
        __syncthreads();
    }

    // publish per-wave partials
    if (role < 2) {
        part[w][l][0] = fminf(fminf(m0, m1), fminf(m2, m3));
    } else {
        part[w][l][0] = b0; part[w][l][1] = b1;
        part[w][l][2] = b2; part[w][l][3] = b3;
    }
    __syncthreads();

    // wave 0 merges and reduces
    float contrib = 0.f;
    if (threadIdx.x < QB) {
        if (valid) {
            float inv_r = 1.0f / radius[b];
            if (role < 2) {
                float best = fminf(fminf(part[0][l][0], part[1][l][0]),
                                   fminf(part[2][l][0], part[3][l][0]));
                float wgt = (role == 0) ? 0.8f : 0.2f;
                contrib = wgt * inv_r * (na + best);
            } else {
                float s0 = FLT_INF, s1 = FLT_INF, s2 = FLT_INF, s3 = FLT_INF;
                #pragma unroll
                for (int ww = 0; ww < NWAVE; ++ww) {
                    #pragma unroll
                    for (int k = 0; k < 4; ++k) {
                        float m = part[ww][l][k], n;
                        if (m < s3) {
                            n = fminf(s0, m); m = fmaxf(s0, m); s0 = n;
                            n = fminf(s1, m); m = fmaxf(s1, m); s1 = n;
                            n = fminf(s2, m); m = fmaxf(s2, m); s2 = n;
                            s3 = m;
                        }
                    }
                }
                float ss[4] = {s0, s1, s2, s3};
                float s = 0.f;
                #pragma unroll
                for (int k = 0; k < 4; ++k) {
                    float d2 = fmaxf(na + ss[k], EPSV);
                    float dist = sqrtf(d2);
                    float wgt = __expf(-d2 * INV_H2);
                    s += (RADIUS - dist) * wgt;
                }
                contrib = s;
            }
        }
    }
    if (threadIdx.x < 64) {
        #pragma unroll
        for (int off = 32; off > 0; off >>= 1) contrib += __shfl_down(contrib, off, 64);
        if (threadIdx.x == 0) atomicAdd(&acc[role < 2 ? 0 : 1], contrib);
    }
}

__global__ void upsample_final_kernel(const float* __restrict__ acc,
                                      float* __restrict__ out,
                                      float invCd, float invUni)
{
    out[0] = fmaf(acc[0], invCd, 0.1f * acc[1] * invUni);
}

extern "C" void kernel_launch(void* const* d_in, const int* in_sizes, int n_in,
                              void* d_out, int out_size, void* d_ws, size_t ws_size,
                              hipStream_t stream) {
    const float* pred   = (const float*)d_in[0];
    const float* gt     = (const float*)d_in[1];
    const float* radius = (const float*)d_in[2];
    float* out = (float*)d_out;
    float* acc = (float*)d_ws;

    int B = in_sizes[2];                 // pcd_radius has B elements
    int N = in_sizes[0] / (3 * B);       // pred is B*N*3

    hipMemsetAsync(acc, 0, 2 * sizeof(float), stream);

    int chunksPerBatch = (N + QB - 1) / QB;
    int blocks = 3 * B * chunksPerBatch;
    upsample_scan_kernel<<<blocks, THREADS, 0, stream>>>(pred, gt, radius, acc,
                                                         B, N, chunksPerBatch);

    float invCd  = 1.0f / ((float)B * (float)N);
    float invUni = 1.0f / ((float)B * (float)N * 4.0f);
    upsample_final_kernel<<<1, 1, 0, stream>>>(acc, out, invCd, invUni);
}